// Round 11
// baseline (658.819 us; speedup 1.0000x reference)
//
#include <hip/hip_runtime.h>

// Correlation / cost volume:
// corr[n, dy*9+dx, h, w] = sum_c f0[n,c,h,w] * f1[n,c,h+dy-4,w+dx-4] (0-padded)
// N=8, C=256, H=W=128 -> D=9, 81 disp channels.
//
// R10 post-mortem: 180us, conflicts 0, no LDS -- yet VALUBusy ~25%. Binding
// pipe (by arithmetic): vector-L1 LINE throughput. Each wave64 float4 load =
// 16 x 64B lines of TCP service, hit or miss. R10: 4 loads/chunk = 64 lines
// per 72 VALU-cycles -> ~123us of L1 service alone.
// R11: load ONLY f0 + f1-mid (2 loads, the coalescing optimum -- every byte
// needed); derive l/r windows from NEIGHBOR LANES via __shfl_up/down
// (ds_bpermute: LDS pipe, no L1 slots). Boundary lanes (q=0/31, incl. the
// lane 31<->32 row seam) were already zero-masked by okL/okR selects.
//  - thread: 4 px x 9 dx x 1 dy; acc = 9 float4 = 36 VGPR.
//  - block = 3 indep waves (dy = dyg*3 + j), no barriers, no LDS storage.
//  - 4-slot register ring (a,m), prefetch 3 chunks ahead.
//  - grid 1536 = 8n x 64hp x 3dyg, XCD-swizzled (image = XCD).

#define DD    9
#define Hh    128
#define Ww    128
#define Cc    256
#define PLANE 16384

__global__ __launch_bounds__(192) __attribute__((amdgpu_waves_per_eu(4, 8)))
void corr_kernel(const float* __restrict__ f0,
                 const float* __restrict__ f1,
                 float* __restrict__ out) {
    const int tid  = threadIdx.x;
    const int j    = tid >> 6;         // wave: dy = dyg*3 + j
    const int lane = tid & 63;
    const int row  = lane >> 5;        // 0..1
    const int q    = lane & 31;        // w-quad

    const int bid = blockIdx.x;
    const int n   = bid & 7;           // XCD swizzle: image per XCD
    const int rem = bid >> 3;
    const int hp  = rem / 3;           // 0..63
    const int dyg = rem % 3;           // innermost: f1-row reuse in time
    const int dy  = dyg * 3 + j;
    const int h   = hp * 2 + row;

    const int wq = 4 * q;
    const int gh = h + dy - 4;
    const bool rowok = ((unsigned)gh < (unsigned)Hh);
    const bool okL   = (q >= 1);
    const bool okR   = (q <= 30);

    // invariant lane offsets (floats); clamped so every address is in-bounds
    const int f0off = h * Ww + wq;
    const int f1mid = (rowok ? gh : 0) * Ww + wq;

    const float* p0 = f0 + (size_t)n * Cc * PLANE;   // uniform chunk ptrs
    const float* p1 = f1 + (size_t)n * Cc * PLANE;

    const float4 z4 = make_float4(0.f, 0.f, 0.f, 0.f);

    float4 acc[DD];
#pragma unroll
    for (int d = 0; d < DD; ++d) acc[d] = z4;

    // 4-slot ring: f0 quad a*, f1 mid quad m*
    float4 a0, m0, a1, m1, a2, m2, a3, m3;

#define LOADS(S)                                                         \
    {                                                                    \
        a##S = *(const float4*)(p0 + f0off);                             \
        m##S = *(const float4*)(p1 + f1mid);                             \
        p0 += PLANE; p1 += PLANE;                                        \
    }

#define COMPS(S)                                                         \
    {                                                                    \
        const float4 av = rowok ? a##S : z4;                             \
        const float4 mv = m##S;                                          \
        float4 lv, rv;                                                   \
        lv.x = __shfl_up(mv.x, 1);   lv.y = __shfl_up(mv.y, 1);          \
        lv.z = __shfl_up(mv.z, 1);   lv.w = __shfl_up(mv.w, 1);          \
        rv.x = __shfl_down(mv.x, 1); rv.y = __shfl_down(mv.y, 1);        \
        rv.z = __shfl_down(mv.z, 1); rv.w = __shfl_down(mv.w, 1);        \
        lv = okL ? lv : z4;                                              \
        rv = okR ? rv : z4;                                              \
        const float w[12] = {lv.x, lv.y, lv.z, lv.w,                     \
                             mv.x, mv.y, mv.z, mv.w,                     \
                             rv.x, rv.y, rv.z, rv.w};                    \
        _Pragma("unroll")                                                \
        for (int dx = 0; dx < DD; ++dx) {                                \
            acc[dx].x += av.x * w[dx + 0];                               \
            acc[dx].y += av.y * w[dx + 1];                               \
            acc[dx].z += av.z * w[dx + 2];                               \
            acc[dx].w += av.w * w[dx + 3];                               \
        }                                                                \
    }

    LOADS(0);           // chunk 0
    LOADS(1);           // chunk 1
    LOADS(2);           // chunk 2

    for (int i = 0; i < 252; i += 4) {
        LOADS(3); COMPS(0);        // load i+3, compute i
        LOADS(0); COMPS(1);
        LOADS(1); COMPS(2);
        LOADS(2); COMPS(3);
    }
    LOADS(3);                       // chunk 255
    COMPS(0); COMPS(1); COMPS(2); COMPS(3);   // chunks 252..255

    // epilogue: 9 quad stores
    float* outp = out + ((size_t)n * (DD * DD) + (size_t)dy * DD) * PLANE
                      + (size_t)h * Ww + wq;
#pragma unroll
    for (int dx = 0; dx < DD; ++dx)
        *(float4*)(outp + (size_t)dx * PLANE) = acc[dx];
}

extern "C" void kernel_launch(void* const* d_in, const int* in_sizes, int n_in,
                              void* d_out, int out_size, void* d_ws, size_t ws_size,
                              hipStream_t stream) {
    const float* f0 = (const float*)d_in[0];
    const float* f1 = (const float*)d_in[1];
    float* out = (float*)d_out;
    // grid: 8 n * 64 h-pairs * 3 dyg = 1536 blocks, 192 threads (3 indep waves)
    corr_kernel<<<dim3(1536), dim3(192), 0, stream>>>(f0, f1, out);
}

// Round 12
// 491.638 us; speedup vs baseline: 1.3400x; 1.3400x over previous
//
#include <hip/hip_runtime.h>

// Correlation / cost volume:
// corr[n, dy*9+dx, h, w] = sum_c f0[n,c,h,w] * f1[n,c,h+dy-4,w+dx-4] (0-padded)
// N=8, C=256, H=W=128 -> D=9, 81 disp channels.
//
// R10/R11 model: binding pipe is vector-L1 LINE service (~1 line/cyc/CU),
// independent of hit/miss. R10 = 64 lines per 72 VALU-cyc chunk (0.89).
// R12: PX=8 -> 64 lines per 144 VALU-cyc (0.44). Loads per chunk: f0 2 quads
// + f1-mid 2 quads only; edge quads (w[0..3], w[12..15]) come from NEIGHBOR
// LANES via __shfl_up/down (LDS pipe, ~48cy << 32 saved line-cyc).
// R11's spill cause was amdgpu_waves_per_eu(4,8); (2,8) is proven (R6/R8:
// VGPR 112-116 no spill). Check WRITE_SIZE ~= 41.5MB to confirm no spill.
//  - wave = 4 h-rows x 128 w (lane: r=lane>>4, o=lane&15), thread 8px x 9dx.
//  - block = 3 indep waves (dy = dyg*3 + j), no barriers, no LDS storage.
//  - ring 3-slot (2 ahead): 8 outstanding loads/wave.
//  - grid 768 = 8n x 32hp x 3dyg, XCD-swizzled (image = XCD), 3 blocks/CU.

#define DD    9
#define Hh    128
#define Ww    128
#define Cc    256
#define PLANE 16384

__global__ __launch_bounds__(192) __attribute__((amdgpu_waves_per_eu(2, 8)))
void corr_kernel(const float* __restrict__ f0,
                 const float* __restrict__ f1,
                 float* __restrict__ out) {
    const int tid  = threadIdx.x;
    const int j    = tid >> 6;         // wave: dy = dyg*3 + j
    const int lane = tid & 63;
    const int r    = lane >> 4;        // 0..3 (h-row)
    const int o    = lane & 15;        // octet (8 px) 0..15

    const int bid = blockIdx.x;
    const int n   = bid & 7;           // XCD swizzle: image per XCD
    const int rem = bid >> 3;          // 0..95
    const int hp  = rem / 3;           // 0..31
    const int dyg = rem % 3;           // innermost: f1-row reuse in time
    const int dy  = dyg * 3 + j;
    const int h   = hp * 4 + r;

    const int gh = h + dy - 4;
    const bool rowok = ((unsigned)gh < (unsigned)Hh);
    const bool okL   = (o >= 1);
    const bool okR   = (o <= 14);

    const int f0off = h * Ww + 8 * o;
    const int f1off = (rowok ? gh : 0) * Ww + 8 * o;   // clamped in-bounds

    const float* p0 = f0 + (size_t)n * Cc * PLANE;     // advance per chunk
    const float* p1 = f1 + (size_t)n * Cc * PLANE;

    const float4 z4 = make_float4(0.f, 0.f, 0.f, 0.f);

    float4 acc[DD][2];
#pragma unroll
    for (int d = 0; d < DD; ++d) { acc[d][0] = z4; acc[d][1] = z4; }

    // 3-slot ring: f0 quads a*0,a*1; f1-mid quads m*0,m*1
    float4 aA0, aA1, mA0, mA1;
    float4 aB0, aB1, mB0, mB1;
    float4 aC0, aC1, mC0, mC1;

#define LOADS(S)                                                         \
    {                                                                    \
        a##S##0 = *(const float4*)(p0 + f0off);                          \
        a##S##1 = *(const float4*)(p0 + f0off + 4);                      \
        m##S##0 = *(const float4*)(p1 + f1off);                          \
        m##S##1 = *(const float4*)(p1 + f1off + 4);                      \
        p0 += PLANE; p1 += PLANE;                                        \
    }

#define COMPS(S)                                                         \
    {                                                                    \
        const float4 av0 = rowok ? a##S##0 : z4;                         \
        const float4 av1 = rowok ? a##S##1 : z4;                         \
        const float4 mv0 = m##S##0;                                      \
        const float4 mv1 = m##S##1;                                      \
        float4 lv, rv;                                                   \
        lv.x = __shfl_up(mv1.x, 1);   lv.y = __shfl_up(mv1.y, 1);        \
        lv.z = __shfl_up(mv1.z, 1);   lv.w = __shfl_up(mv1.w, 1);        \
        rv.x = __shfl_down(mv0.x, 1); rv.y = __shfl_down(mv0.y, 1);      \
        rv.z = __shfl_down(mv0.z, 1); rv.w = __shfl_down(mv0.w, 1);      \
        lv = okL ? lv : z4;                                              \
        rv = okR ? rv : z4;                                              \
        const float w[16] = {lv.x,  lv.y,  lv.z,  lv.w,                  \
                             mv0.x, mv0.y, mv0.z, mv0.w,                 \
                             mv1.x, mv1.y, mv1.z, mv1.w,                 \
                             rv.x,  rv.y,  rv.z,  rv.w};                 \
        _Pragma("unroll")                                                \
        for (int dx = 0; dx < DD; ++dx) {                                \
            acc[dx][0].x += av0.x * w[dx + 0];                           \
            acc[dx][0].y += av0.y * w[dx + 1];                           \
            acc[dx][0].z += av0.z * w[dx + 2];                           \
            acc[dx][0].w += av0.w * w[dx + 3];                           \
            acc[dx][1].x += av1.x * w[dx + 4];                           \
            acc[dx][1].y += av1.y * w[dx + 5];                           \
            acc[dx][1].z += av1.z * w[dx + 6];                           \
            acc[dx][1].w += av1.w * w[dx + 7];                           \
        }                                                                \
    }

    LOADS(A);            // chunk 0
    LOADS(B);            // chunk 1

    for (int it = 0; it < 84; ++it) {       // chunks 0..251
        LOADS(C); COMPS(A);
        LOADS(A); COMPS(B);
        LOADS(B); COMPS(C);
    }
    LOADS(C); COMPS(A);  // load 254, compute 252
    LOADS(A); COMPS(B);  // load 255, compute 253
    COMPS(C);            // 254
    COMPS(A);            // 255

    // epilogue: 9 dx x 2 quad stores
    float* outp = out + ((size_t)n * (DD * DD) + (size_t)dy * DD) * PLANE
                      + (size_t)h * Ww + 8 * o;
#pragma unroll
    for (int dx = 0; dx < DD; ++dx) {
        float* op = outp + (size_t)dx * PLANE;
        *(float4*)(op)     = acc[dx][0];
        *(float4*)(op + 4) = acc[dx][1];
    }
}

extern "C" void kernel_launch(void* const* d_in, const int* in_sizes, int n_in,
                              void* d_out, int out_size, void* d_ws, size_t ws_size,
                              hipStream_t stream) {
    const float* f0 = (const float*)d_in[0];
    const float* f1 = (const float*)d_in[1];
    float* out = (float*)d_out;
    // grid: 8 n * 32 hp * 3 dyg = 768 blocks, 192 threads (3 indep waves)
    corr_kernel<<<dim3(768), dim3(192), 0, stream>>>(f0, f1, out);
}